// Round 1
// baseline (21502.922 us; speedup 1.0000x reference)
//
#include <hip/hip_runtime.h>
#include <hip/hip_bf16.h>
#include <cstdint>

#define SENTW 0x7F7F7F7Fu   // float ~3.39e38; |h|<1 so never produced by LSTM

__device__ __forceinline__ float sigf(float x){ return 1.f/(1.f+expf(-x)); }

// ---------------- embedding: X[s] = concat(word_emb[x[s]], pos_emb[x_pos[s]]) ----------------
__global__ __launch_bounds__(256) void k_embed(
    const int* __restrict__ x, const int* __restrict__ xp,
    const float* __restrict__ we, const float* __restrict__ pe,
    float* __restrict__ X)
{
  const int s = blockIdx.x, t = threadIdx.x;
  float4* xr = (float4*)(X + (size_t)s*1024);
  if (t < 224){                                  // 224*4 = 896 word dims
    const float4* wr = (const float4*)(we + (size_t)x[s]*896);
    xr[t] = wr[t];
  } else {                                       // 32*4 = 128 pos dims
    const float4* pr = (const float4*)(pe + (size_t)xp[s]*128);
    xr[t] = pr[t-224];
  }
}

// ---------------- fp32 GEMM: C[M,N] = A[M,K] * B[N,K]^T + bias[n] + (*cadd) ----------------
// BM=BN=128, BK=16, 256 threads, 8x8 micro-tile.
__global__ __launch_bounds__(256,2) void k_gemm_abT(
    const float* __restrict__ A, const float* __restrict__ B, float* __restrict__ C,
    int M, int N, int K,
    const float* __restrict__ bias, const float* __restrict__ cadd)
{
  __shared__ float As[16][132];
  __shared__ float Bs[16][132];
  const int tid = threadIdx.x;
  const int m0 = blockIdx.y*128, n0 = blockIdx.x*128;
  const int r  = tid>>1, cq = tid&1;       // loader mapping: row r, k-half cq
  const int ty = tid>>4, tx = tid&15;      // compute mapping

  float acc[8][8];
  #pragma unroll
  for (int i=0;i<8;i++)
    #pragma unroll
    for (int j=0;j<8;j++) acc[i][j]=0.f;

  for (int k0=0;k0<K;k0+=16){
    const float* ap = A + (size_t)(m0+r)*K + k0 + cq*8;
    const float* bp = B + (size_t)(n0+r)*K + k0 + cq*8;
    float4 a0 = *(const float4*)ap;
    float4 a1 = *(const float4*)(ap+4);
    float4 b0 = *(const float4*)bp;
    float4 b1 = *(const float4*)(bp+4);
    __syncthreads();   // previous iteration's LDS reads done
    As[cq*8+0][r]=a0.x; As[cq*8+1][r]=a0.y; As[cq*8+2][r]=a0.z; As[cq*8+3][r]=a0.w;
    As[cq*8+4][r]=a1.x; As[cq*8+5][r]=a1.y; As[cq*8+6][r]=a1.z; As[cq*8+7][r]=a1.w;
    Bs[cq*8+0][r]=b0.x; Bs[cq*8+1][r]=b0.y; Bs[cq*8+2][r]=b0.z; Bs[cq*8+3][r]=b0.w;
    Bs[cq*8+4][r]=b1.x; Bs[cq*8+5][r]=b1.y; Bs[cq*8+6][r]=b1.z; Bs[cq*8+7][r]=b1.w;
    __syncthreads();
    #pragma unroll
    for (int k=0;k<16;k++){
      float4 av0 = *(const float4*)&As[k][ty*8];
      float4 av1 = *(const float4*)&As[k][ty*8+4];
      float4 bv0 = *(const float4*)&Bs[k][tx*8];
      float4 bv1 = *(const float4*)&Bs[k][tx*8+4];
      float a[8]={av0.x,av0.y,av0.z,av0.w,av1.x,av1.y,av1.z,av1.w};
      float b[8]={bv0.x,bv0.y,bv0.z,bv0.w,bv1.x,bv1.y,bv1.z,bv1.w};
      #pragma unroll
      for (int i=0;i<8;i++)
        #pragma unroll
        for (int j=0;j<8;j++)
          acc[i][j] = fmaf(a[i],b[j],acc[i][j]);
    }
  }

  float cb = cadd ? *cadd : 0.f;
  float bv[8];
  if (bias){
    float4 t0 = *(const float4*)&bias[n0+tx*8];
    float4 t1 = *(const float4*)&bias[n0+tx*8+4];
    bv[0]=t0.x; bv[1]=t0.y; bv[2]=t0.z; bv[3]=t0.w;
    bv[4]=t1.x; bv[5]=t1.y; bv[6]=t1.z; bv[7]=t1.w;
  } else {
    #pragma unroll
    for (int j=0;j<8;j++) bv[j]=0.f;
  }
  #pragma unroll
  for (int i=0;i<8;i++){
    float* cp = C + (size_t)(m0+ty*8+i)*N + n0+tx*8;
    float4 o0, o1;
    o0.x=acc[i][0]+bv[0]+cb; o0.y=acc[i][1]+bv[1]+cb;
    o0.z=acc[i][2]+bv[2]+cb; o0.w=acc[i][3]+bv[3]+cb;
    o1.x=acc[i][4]+bv[4]+cb; o1.y=acc[i][5]+bv[5]+cb;
    o1.z=acc[i][6]+bv[6]+cb; o1.w=acc[i][7]+bv[7]+cb;
    *(float4*)cp = o0; *(float4*)(cp+4) = o1;
  }
}

// ---------------- LSTM scan, one layer, both directions ----------------
// grid = 128 WGs: blockIdx<64 -> fwd, else bwd. Each WG owns 8 hidden units
// (32 rows of W_hh, register-resident). Sync = data-as-flag: h values stored
// with agent-scope atomics, consumers spin on the values vs SENTW sentinel.
__global__ __launch_bounds__(256,1) void k_lstm_scan(
    const float* __restrict__ pre,   // [1024][4096]: dir*2048 + gate*512 + unit
    const float* __restrict__ Whh,   // [2][2048][512] (this layer)
    float* __restrict__ out)         // [1024][1024]; fwd cols 0..511, bwd 512..1023
{
  const int wg  = blockIdx.x;
  const int dir = wg >> 6;
  const int w   = wg & 63;
  const int tid = threadIdx.x;
  const int kc  = tid & 7;         // k-chunk (64 floats)
  const int rl  = tid >> 3;        // local row 0..31
  const int gate= rl & 3;          // i,f,g,o
  const int ul  = rl >> 2;         // local unit 0..7
  const int unit= w*8 + ul;
  const int grow= gate*512 + unit; // row in W_hh
  const int k0  = kc*64;

  // register-resident weights: this thread's 64 elements of its row
  float wreg[64];
  {
    const float* wp = Whh + ((size_t)dir*2048 + grow)*512 + k0;
    #pragma unroll
    for (int j=0;j<16;j++){
      float4 q = *(const float4*)(wp + 4*j);
      wreg[4*j+0]=q.x; wreg[4*j+1]=q.y; wreg[4*j+2]=q.z; wreg[4*j+3]=q.w;
    }
  }

  unsigned* ob = (unsigned*)out;
  float c = 0.f;
  const int base = (tid & 32);     // base lane (within wave) of this unit's gate group

  for (int t=0;t<1024;t++){
    const int s  = dir ? (1023 - t) : t;
    const int sp = dir ? (s + 1) : (s - 1);

    // prefetch input-projection value (independent of h -> issues before poll)
    float preval = 0.f;
    if ((tid&7)==0) preval = pre[(size_t)s*4096 + (size_t)dir*2048 + grow];

    float accv = 0.f;
    if (t > 0){
      unsigned* hp = ob + (size_t)sp*1024 + dir*512 + k0;
      unsigned vbuf[64];
      for(;;){
        #pragma unroll
        for (int j=0;j<64;j++)
          vbuf[j] = __hip_atomic_load(hp + j, __ATOMIC_RELAXED, __HIP_MEMORY_SCOPE_AGENT);
        unsigned okc = 1u;
        #pragma unroll
        for (int j=0;j<64;j++)
          okc &= (unsigned)(vbuf[j] != SENTW);
        if (okc) break;
      }
      float p0=0.f,p1=0.f,p2=0.f,p3=0.f;
      #pragma unroll
      for (int j=0;j<16;j++){
        p0 = fmaf(wreg[4*j+0], __uint_as_float(vbuf[4*j+0]), p0);
        p1 = fmaf(wreg[4*j+1], __uint_as_float(vbuf[4*j+1]), p1);
        p2 = fmaf(wreg[4*j+2], __uint_as_float(vbuf[4*j+2]), p2);
        p3 = fmaf(wreg[4*j+3], __uint_as_float(vbuf[4*j+3]), p3);
      }
      accv = (p0+p1)+(p2+p3);
      accv += __shfl_xor(accv, 1);
      accv += __shfl_xor(accv, 2);
      accv += __shfl_xor(accv, 4);   // lanes with tid&7==0 hold full dot
    }
    float g = accv + preval;
    // gather the 4 gates of this unit (they live at lanes base+{0,8,16,24})
    float gi = __shfl(g, base+0);
    float gf = __shfl(g, base+8);
    float gg = __shfl(g, base+16);
    float go = __shfl(g, base+24);
    if ((tid&31)==0){
      c = sigf(gf)*c + sigf(gi)*tanhf(gg);
      float h = sigf(go)*tanhf(c);
      __hip_atomic_store(ob + (size_t)s*1024 + dir*512 + unit,
                         __float_as_uint(h), __ATOMIC_RELAXED, __HIP_MEMORY_SCOPE_AGENT);
    }
  }
}

// ---------------- row softmax, in place ----------------
__global__ __launch_bounds__(256) void k_softmax(float* __restrict__ P){
  __shared__ float redm[4], reds[4];
  const int i = blockIdx.x, tid = threadIdx.x;
  float4 v = *(float4*)&P[(size_t)i*1024 + tid*4];
  float m = fmaxf(fmaxf(v.x,v.y), fmaxf(v.z,v.w));
  #pragma unroll
  for (int o=32;o;o>>=1) m = fmaxf(m, __shfl_xor(m,o));
  if ((tid&63)==0) redm[tid>>6] = m;
  __syncthreads();
  m = fmaxf(fmaxf(redm[0],redm[1]), fmaxf(redm[2],redm[3]));
  v.x = expf(v.x-m); v.y = expf(v.y-m); v.z = expf(v.z-m); v.w = expf(v.w-m);
  float su = v.x+v.y+v.z+v.w;
  #pragma unroll
  for (int o=32;o;o>>=1) su += __shfl_xor(su,o);
  if ((tid&63)==0) reds[tid>>6] = su;
  __syncthreads();
  su = reds[0]+reds[1]+reds[2]+reds[3];
  float inv = 1.f/su;
  v.x*=inv; v.y*=inv; v.z*=inv; v.w*=inv;
  *(float4*)&P[(size_t)i*1024 + tid*4] = v;
}

extern "C" void kernel_launch(void* const* d_in, const int* in_sizes, int n_in,
                              void* d_out, int out_size, void* d_ws, size_t ws_size,
                              hipStream_t stream)
{
  const int*   x    = (const int*)d_in[0];
  const int*   xp   = (const int*)d_in[1];
  const float* we   = (const float*)d_in[2];
  const float* pe   = (const float*)d_in[3];
  const float* Wih  = (const float*)d_in[4];   // [2][2][2048][1024]
  const float* Whh  = (const float*)d_in[5];   // [2][2][2048][512]
  const float* bl   = (const float*)d_in[6];   // [2][2][2048]
  const float* Wh   = (const float*)d_in[7];
  const float* bh   = (const float*)d_in[8];
  const float* Wd   = (const float*)d_in[9];
  const float* bd   = (const float*)d_in[10];
  const float* Wbi  = (const float*)d_in[11];
  const float* bbi  = (const float*)d_in[12];
  float* outp = (float*)d_out;

  // workspace layout (28 MB), with reuse after the scans:
  char* ws = (char*)d_ws;
  float* X0   = (float*)(ws);                  // [0,4M)   embeddings
  float* pre  = (float*)(ws + ((size_t)4<<20));// [4M,20M) input projections
  float* out0 = (float*)(ws + ((size_t)20<<20));// [20M,24M)
  float* out1 = (float*)(ws + ((size_t)24<<20));// [24M,28M)
  float* head = (float*)(ws);                  // reuse [0,4M)
  float* dep  = (float*)(ws + ((size_t)4<<20));// reuse [4M,8M)
  float* Ubuf = (float*)(ws + ((size_t)8<<20));// reuse [8M,12M)

  // sentinel-init the scan outputs (data-as-flag scheme), every launch
  hipMemsetAsync(out0, 0x7F, (size_t)4<<20, stream);
  hipMemsetAsync(out1, 0x7F, (size_t)4<<20, stream);

  dim3 blk(256);
  k_embed<<<1024, blk, 0, stream>>>(x, xp, we, pe, X0);

  // layer 0: pre = X0 * Wih[0]^T + b[0]  (both dirs stacked: N=4096)
  k_gemm_abT<<<dim3(32,8), blk, 0, stream>>>(X0, Wih, pre, 1024, 4096, 1024, bl, nullptr);
  k_lstm_scan<<<128, blk, 0, stream>>>(pre, Whh, out0);

  // layer 1
  k_gemm_abT<<<dim3(32,8), blk, 0, stream>>>(out0, Wih + (size_t)4096*1024, pre,
                                             1024, 4096, 1024, bl + 4096, nullptr);
  k_lstm_scan<<<128, blk, 0, stream>>>(pre, Whh + (size_t)2*2048*512, out1);

  // biaffine: head = out1*Wh^T+bh ; dep = out1*Wd^T+bd ; U = dep*Wbi^T ; scores = head*U^T + bbi
  k_gemm_abT<<<dim3(8,8), blk, 0, stream>>>(out1, Wh, head, 1024, 1024, 1024, bh, nullptr);
  k_gemm_abT<<<dim3(8,8), blk, 0, stream>>>(out1, Wd, dep,  1024, 1024, 1024, bd, nullptr);
  k_gemm_abT<<<dim3(8,8), blk, 0, stream>>>(dep,  Wbi, Ubuf,1024, 1024, 1024, nullptr, nullptr);
  k_gemm_abT<<<dim3(8,8), blk, 0, stream>>>(head, Ubuf, outp,1024, 1024, 1024, nullptr, bbi);

  k_softmax<<<1024, blk, 0, stream>>>(outp);
}

// Round 2
// 8344.833 us; speedup vs baseline: 2.5768x; 2.5768x over previous
//
#include <hip/hip_runtime.h>
#include <hip/hip_bf16.h>
#include <cstdint>

#define SENTW 0x7F7F7F7Fu   // float ~3.39e38; |h|<1 so never produced by LSTM

__device__ __forceinline__ float sigf(float x){ return 1.f/(1.f+expf(-x)); }

// ---------------- embedding: X[s] = concat(word_emb[x[s]], pos_emb[x_pos[s]]) ----------------
__global__ __launch_bounds__(256) void k_embed(
    const int* __restrict__ x, const int* __restrict__ xp,
    const float* __restrict__ we, const float* __restrict__ pe,
    float* __restrict__ X)
{
  const int s = blockIdx.x, t = threadIdx.x;
  float4* xr = (float4*)(X + (size_t)s*1024);
  if (t < 224){                                  // 224*4 = 896 word dims
    const float4* wr = (const float4*)(we + (size_t)x[s]*896);
    xr[t] = wr[t];
  } else {                                       // 32*4 = 128 pos dims
    const float4* pr = (const float4*)(pe + (size_t)xp[s]*128);
    xr[t] = pr[t-224];
  }
}

// ---------------- fp32 GEMM: C[M,N] = A[M,K] * B[N,K]^T + bias[n] + (*cadd) ----------------
// BM=BN=128, BK=16, 256 threads, 8x8 micro-tile.
__global__ __launch_bounds__(256,2) void k_gemm_abT(
    const float* __restrict__ A, const float* __restrict__ B, float* __restrict__ C,
    int M, int N, int K,
    const float* __restrict__ bias, const float* __restrict__ cadd)
{
  __shared__ float As[16][132];
  __shared__ float Bs[16][132];
  const int tid = threadIdx.x;
  const int m0 = blockIdx.y*128, n0 = blockIdx.x*128;
  const int r  = tid>>1, cq = tid&1;       // loader mapping: row r, k-half cq
  const int ty = tid>>4, tx = tid&15;      // compute mapping

  float acc[8][8];
  #pragma unroll
  for (int i=0;i<8;i++)
    #pragma unroll
    for (int j=0;j<8;j++) acc[i][j]=0.f;

  for (int k0=0;k0<K;k0+=16){
    const float* ap = A + (size_t)(m0+r)*K + k0 + cq*8;
    const float* bp = B + (size_t)(n0+r)*K + k0 + cq*8;
    float4 a0 = *(const float4*)ap;
    float4 a1 = *(const float4*)(ap+4);
    float4 b0 = *(const float4*)bp;
    float4 b1 = *(const float4*)(bp+4);
    __syncthreads();   // previous iteration's LDS reads done
    As[cq*8+0][r]=a0.x; As[cq*8+1][r]=a0.y; As[cq*8+2][r]=a0.z; As[cq*8+3][r]=a0.w;
    As[cq*8+4][r]=a1.x; As[cq*8+5][r]=a1.y; As[cq*8+6][r]=a1.z; As[cq*8+7][r]=a1.w;
    Bs[cq*8+0][r]=b0.x; Bs[cq*8+1][r]=b0.y; Bs[cq*8+2][r]=b0.z; Bs[cq*8+3][r]=b0.w;
    Bs[cq*8+4][r]=b1.x; Bs[cq*8+5][r]=b1.y; Bs[cq*8+6][r]=b1.z; Bs[cq*8+7][r]=b1.w;
    __syncthreads();
    #pragma unroll
    for (int k=0;k<16;k++){
      float4 av0 = *(const float4*)&As[k][ty*8];
      float4 av1 = *(const float4*)&As[k][ty*8+4];
      float4 bv0 = *(const float4*)&Bs[k][tx*8];
      float4 bv1 = *(const float4*)&Bs[k][tx*8+4];
      float a[8]={av0.x,av0.y,av0.z,av0.w,av1.x,av1.y,av1.z,av1.w};
      float b[8]={bv0.x,bv0.y,bv0.z,bv0.w,bv1.x,bv1.y,bv1.z,bv1.w};
      #pragma unroll
      for (int i=0;i<8;i++)
        #pragma unroll
        for (int j=0;j<8;j++)
          acc[i][j] = fmaf(a[i],b[j],acc[i][j]);
    }
  }

  float cb = cadd ? *cadd : 0.f;
  float bv[8];
  if (bias){
    float4 t0 = *(const float4*)&bias[n0+tx*8];
    float4 t1 = *(const float4*)&bias[n0+tx*8+4];
    bv[0]=t0.x; bv[1]=t0.y; bv[2]=t0.z; bv[3]=t0.w;
    bv[4]=t1.x; bv[5]=t1.y; bv[6]=t1.z; bv[7]=t1.w;
  } else {
    #pragma unroll
    for (int j=0;j<8;j++) bv[j]=0.f;
  }
  #pragma unroll
  for (int i=0;i<8;i++){
    float* cp = C + (size_t)(m0+ty*8+i)*N + n0+tx*8;
    float4 o0, o1;
    o0.x=acc[i][0]+bv[0]+cb; o0.y=acc[i][1]+bv[1]+cb;
    o0.z=acc[i][2]+bv[2]+cb; o0.w=acc[i][3]+bv[3]+cb;
    o1.x=acc[i][4]+bv[4]+cb; o1.y=acc[i][5]+bv[5]+cb;
    o1.z=acc[i][6]+bv[6]+cb; o1.w=acc[i][7]+bv[7]+cb;
    *(float4*)cp = o0; *(float4*)(cp+4) = o1;
  }
}

// ---------------- LSTM scan, one layer, both directions ----------------
// grid = 128 WGs: blockIdx<64 -> fwd, else bwd. Each WG owns 8 hidden units
// (32 rows of W_hh, register-resident). Sync = data-as-flag via sentinel,
// but each thread polls ONLY its own 2 dwords of h (single producer each),
// deposits them in double-buffered LDS; one barrier; dot-product reads LDS.
// This removes the 32x-redundant device-scope poll storm of R0.
__global__ __launch_bounds__(256,1) void k_lstm_scan(
    const float* __restrict__ pre,   // [1024][4096]: dir*2048 + gate*512 + unit
    const float* __restrict__ Whh,   // [2][2048][512] (this layer)
    float* __restrict__ out)         // [1024][1024]; fwd cols 0..511, bwd 512..1023
{
  const int wg  = blockIdx.x;
  const int dir = wg >> 6;
  const int w   = wg & 63;
  const int tid = threadIdx.x;
  const int kc  = tid & 7;         // k-chunk (64 floats)
  const int rl  = tid >> 3;        // local row 0..31
  const int gate= rl & 3;          // i,f,g,o
  const int ul  = rl >> 2;         // local unit 0..7
  const int unit= w*8 + ul;
  const int grow= gate*512 + unit; // row in W_hh
  const int k0  = kc*64;

  __shared__ float hsh[2][512];    // double-buffered h of previous step

  // register-resident weights: this thread's 64 elements of its row
  float wreg[64];
  {
    const float* wp = Whh + ((size_t)dir*2048 + grow)*512 + k0;
    #pragma unroll
    for (int j=0;j<16;j++){
      float4 q = *(const float4*)(wp + 4*j);
      wreg[4*j+0]=q.x; wreg[4*j+1]=q.y; wreg[4*j+2]=q.z; wreg[4*j+3]=q.w;
    }
  }

  unsigned* ob = (unsigned*)out;
  float c = 0.f;
  const int base = (tid & 32);     // base lane (within wave) of this unit's gate group

  for (int t=0;t<1024;t++){
    const int s  = dir ? (1023 - t) : t;
    const int sp = dir ? (s + 1) : (s - 1);

    // prefetch input-projection value (independent of h -> issues before poll)
    float preval = 0.f;
    if ((tid&7)==0) preval = pre[(size_t)s*4096 + (size_t)dir*2048 + grow];

    float accv = 0.f;
    if (t > 0){
      // poll ONLY this thread's 2 dwords of h[sp] (one producer WG each)
      unsigned* hp = ob + (size_t)sp*1024 + dir*512 + 2*tid;
      unsigned v0, v1;
      for(;;){
        v0 = __hip_atomic_load(hp + 0, __ATOMIC_RELAXED, __HIP_MEMORY_SCOPE_AGENT);
        v1 = __hip_atomic_load(hp + 1, __ATOMIC_RELAXED, __HIP_MEMORY_SCOPE_AGENT);
        if (v0 != SENTW && v1 != SENTW) break;
      }
      float* hb = hsh[t & 1];
      hb[2*tid]   = __uint_as_float(v0);
      hb[2*tid+1] = __uint_as_float(v1);
      __syncthreads();               // LDS copy complete (also fences prev-buf reuse)

      const float* hv = hb + k0;
      float p0=0.f,p1=0.f,p2=0.f,p3=0.f;
      #pragma unroll
      for (int j=0;j<16;j++){
        float4 q = *(const float4*)(hv + 4*j);
        p0 = fmaf(wreg[4*j+0], q.x, p0);
        p1 = fmaf(wreg[4*j+1], q.y, p1);
        p2 = fmaf(wreg[4*j+2], q.z, p2);
        p3 = fmaf(wreg[4*j+3], q.w, p3);
      }
      accv = (p0+p1)+(p2+p3);
      accv += __shfl_xor(accv, 1);
      accv += __shfl_xor(accv, 2);
      accv += __shfl_xor(accv, 4);   // lanes with tid&7==0 hold full dot
    }
    float g = accv + preval;
    // gather the 4 gates of this unit (they live at lanes base+{0,8,16,24})
    float gi = __shfl(g, base+0);
    float gf = __shfl(g, base+8);
    float gg = __shfl(g, base+16);
    float go = __shfl(g, base+24);
    if ((tid&31)==0){
      c = sigf(gf)*c + sigf(gi)*tanhf(gg);
      float h = sigf(go)*tanhf(c);
      __hip_atomic_store(ob + (size_t)s*1024 + dir*512 + unit,
                         __float_as_uint(h), __ATOMIC_RELAXED, __HIP_MEMORY_SCOPE_AGENT);
    }
  }
}

// ---------------- row softmax, in place ----------------
__global__ __launch_bounds__(256) void k_softmax(float* __restrict__ P){
  __shared__ float redm[4], reds[4];
  const int i = blockIdx.x, tid = threadIdx.x;
  float4 v = *(float4*)&P[(size_t)i*1024 + tid*4];
  float m = fmaxf(fmaxf(v.x,v.y), fmaxf(v.z,v.w));
  #pragma unroll
  for (int o=32;o;o>>=1) m = fmaxf(m, __shfl_xor(m,o));
  if ((tid&63)==0) redm[tid>>6] = m;
  __syncthreads();
  m = fmaxf(fmaxf(redm[0],redm[1]), fmaxf(redm[2],redm[3]));
  v.x = expf(v.x-m); v.y = expf(v.y-m); v.z = expf(v.z-m); v.w = expf(v.w-m);
  float su = v.x+v.y+v.z+v.w;
  #pragma unroll
  for (int o=32;o;o>>=1) su += __shfl_xor(su,o);
  if ((tid&63)==0) reds[tid>>6] = su;
  __syncthreads();
  su = reds[0]+reds[1]+reds[2]+reds[3];
  float inv = 1.f/su;
  v.x*=inv; v.y*=inv; v.z*=inv; v.w*=inv;
  *(float4*)&P[(size_t)i*1024 + tid*4] = v;
}

extern "C" void kernel_launch(void* const* d_in, const int* in_sizes, int n_in,
                              void* d_out, int out_size, void* d_ws, size_t ws_size,
                              hipStream_t stream)
{
  const int*   x    = (const int*)d_in[0];
  const int*   xp   = (const int*)d_in[1];
  const float* we   = (const float*)d_in[2];
  const float* pe   = (const float*)d_in[3];
  const float* Wih  = (const float*)d_in[4];   // [2][2][2048][1024]
  const float* Whh  = (const float*)d_in[5];   // [2][2][2048][512]
  const float* bl   = (const float*)d_in[6];   // [2][2][2048]
  const float* Wh   = (const float*)d_in[7];
  const float* bh   = (const float*)d_in[8];
  const float* Wd   = (const float*)d_in[9];
  const float* bd   = (const float*)d_in[10];
  const float* Wbi  = (const float*)d_in[11];
  const float* bbi  = (const float*)d_in[12];
  float* outp = (float*)d_out;

  // workspace layout (28 MB), with reuse after the scans:
  char* ws = (char*)d_ws;
  float* X0   = (float*)(ws);                  // [0,4M)   embeddings
  float* pre  = (float*)(ws + ((size_t)4<<20));// [4M,20M) input projections
  float* out0 = (float*)(ws + ((size_t)20<<20));// [20M,24M)
  float* out1 = (float*)(ws + ((size_t)24<<20));// [24M,28M)
  float* head = (float*)(ws);                  // reuse [0,4M)
  float* dep  = (float*)(ws + ((size_t)4<<20));// reuse [4M,8M)
  float* Ubuf = (float*)(ws + ((size_t)8<<20));// reuse [8M,12M)

  // sentinel-init the scan outputs (data-as-flag scheme), every launch
  hipMemsetAsync(out0, 0x7F, (size_t)4<<20, stream);
  hipMemsetAsync(out1, 0x7F, (size_t)4<<20, stream);

  dim3 blk(256);
  k_embed<<<1024, blk, 0, stream>>>(x, xp, we, pe, X0);

  // layer 0: pre = X0 * Wih[0]^T + b[0]  (both dirs stacked: N=4096)
  k_gemm_abT<<<dim3(32,8), blk, 0, stream>>>(X0, Wih, pre, 1024, 4096, 1024, bl, nullptr);
  k_lstm_scan<<<128, blk, 0, stream>>>(pre, Whh, out0);

  // layer 1
  k_gemm_abT<<<dim3(32,8), blk, 0, stream>>>(out0, Wih + (size_t)4096*1024, pre,
                                             1024, 4096, 1024, bl + 4096, nullptr);
  k_lstm_scan<<<128, blk, 0, stream>>>(pre, Whh + (size_t)2*2048*512, out1);

  // biaffine: head = out1*Wh^T+bh ; dep = out1*Wd^T+bd ; U = dep*Wbi^T ; scores = head*U^T + bbi
  k_gemm_abT<<<dim3(8,8), blk, 0, stream>>>(out1, Wh, head, 1024, 1024, 1024, bh, nullptr);
  k_gemm_abT<<<dim3(8,8), blk, 0, stream>>>(out1, Wd, dep,  1024, 1024, 1024, bd, nullptr);
  k_gemm_abT<<<dim3(8,8), blk, 0, stream>>>(dep,  Wbi, Ubuf,1024, 1024, 1024, nullptr, nullptr);
  k_gemm_abT<<<dim3(8,8), blk, 0, stream>>>(head, Ubuf, outp,1024, 1024, 1024, nullptr, bbi);

  k_softmax<<<1024, blk, 0, stream>>>(outp);
}

// Round 3
// 6781.998 us; speedup vs baseline: 3.1706x; 1.2304x over previous
//
#include <hip/hip_runtime.h>
#include <hip/hip_bf16.h>
#include <cstdint>

#define SENTW 0x7F7F7F7Fu   // float ~3.39e38; |h|<1 so never produced by LSTM

__device__ __forceinline__ float sigf(float x){ return 1.f/(1.f+expf(-x)); }

// ---------------- embedding: X[s] = concat(word_emb[x[s]], pos_emb[x_pos[s]]) ----------------
__global__ __launch_bounds__(256) void k_embed(
    const int* __restrict__ x, const int* __restrict__ xp,
    const float* __restrict__ we, const float* __restrict__ pe,
    float* __restrict__ X)
{
  const int s = blockIdx.x, t = threadIdx.x;
  float4* xr = (float4*)(X + (size_t)s*1024);
  if (t < 224){                                  // 224*4 = 896 word dims
    const float4* wr = (const float4*)(we + (size_t)x[s]*896);
    xr[t] = wr[t];
  } else {                                       // 32*4 = 128 pos dims
    const float4* pr = (const float4*)(pe + (size_t)xp[s]*128);
    xr[t] = pr[t-224];
  }
}

// ---------------- fp32 GEMM: C[M,N] = A[M,K] * B[N,K]^T + bias[n] + (*cadd) ----------------
// BM=BN=128, BK=16, 256 threads, 8x8 micro-tile.
__global__ __launch_bounds__(256,2) void k_gemm_abT(
    const float* __restrict__ A, const float* __restrict__ B, float* __restrict__ C,
    int M, int N, int K,
    const float* __restrict__ bias, const float* __restrict__ cadd)
{
  __shared__ float As[16][132];
  __shared__ float Bs[16][132];
  const int tid = threadIdx.x;
  const int m0 = blockIdx.y*128, n0 = blockIdx.x*128;
  const int r  = tid>>1, cq = tid&1;       // loader mapping: row r, k-half cq
  const int ty = tid>>4, tx = tid&15;      // compute mapping

  float acc[8][8];
  #pragma unroll
  for (int i=0;i<8;i++)
    #pragma unroll
    for (int j=0;j<8;j++) acc[i][j]=0.f;

  for (int k0=0;k0<K;k0+=16){
    const float* ap = A + (size_t)(m0+r)*K + k0 + cq*8;
    const float* bp = B + (size_t)(n0+r)*K + k0 + cq*8;
    float4 a0 = *(const float4*)ap;
    float4 a1 = *(const float4*)(ap+4);
    float4 b0 = *(const float4*)bp;
    float4 b1 = *(const float4*)(bp+4);
    __syncthreads();   // previous iteration's LDS reads done
    As[cq*8+0][r]=a0.x; As[cq*8+1][r]=a0.y; As[cq*8+2][r]=a0.z; As[cq*8+3][r]=a0.w;
    As[cq*8+4][r]=a1.x; As[cq*8+5][r]=a1.y; As[cq*8+6][r]=a1.z; As[cq*8+7][r]=a1.w;
    Bs[cq*8+0][r]=b0.x; Bs[cq*8+1][r]=b0.y; Bs[cq*8+2][r]=b0.z; Bs[cq*8+3][r]=b0.w;
    Bs[cq*8+4][r]=b1.x; Bs[cq*8+5][r]=b1.y; Bs[cq*8+6][r]=b1.z; Bs[cq*8+7][r]=b1.w;
    __syncthreads();
    #pragma unroll
    for (int k=0;k<16;k++){
      float4 av0 = *(const float4*)&As[k][ty*8];
      float4 av1 = *(const float4*)&As[k][ty*8+4];
      float4 bv0 = *(const float4*)&Bs[k][tx*8];
      float4 bv1 = *(const float4*)&Bs[k][tx*8+4];
      float a[8]={av0.x,av0.y,av0.z,av0.w,av1.x,av1.y,av1.z,av1.w};
      float b[8]={bv0.x,bv0.y,bv0.z,bv0.w,bv1.x,bv1.y,bv1.z,bv1.w};
      #pragma unroll
      for (int i=0;i<8;i++)
        #pragma unroll
        for (int j=0;j<8;j++)
          acc[i][j] = fmaf(a[i],b[j],acc[i][j]);
    }
  }

  float cb = cadd ? *cadd : 0.f;
  float bv[8];
  if (bias){
    float4 t0 = *(const float4*)&bias[n0+tx*8];
    float4 t1 = *(const float4*)&bias[n0+tx*8+4];
    bv[0]=t0.x; bv[1]=t0.y; bv[2]=t0.z; bv[3]=t0.w;
    bv[4]=t1.x; bv[5]=t1.y; bv[6]=t1.z; bv[7]=t1.w;
  } else {
    #pragma unroll
    for (int j=0;j<8;j++) bv[j]=0.f;
  }
  #pragma unroll
  for (int i=0;i<8;i++){
    float* cp = C + (size_t)(m0+ty*8+i)*N + n0+tx*8;
    float4 o0, o1;
    o0.x=acc[i][0]+bv[0]+cb; o0.y=acc[i][1]+bv[1]+cb;
    o0.z=acc[i][2]+bv[2]+cb; o0.w=acc[i][3]+bv[3]+cb;
    o1.x=acc[i][4]+bv[4]+cb; o1.y=acc[i][5]+bv[5]+cb;
    o1.z=acc[i][6]+bv[6]+cb; o1.w=acc[i][7]+bv[7]+cb;
    *(float4*)cp = o0; *(float4*)(cp+4) = o1;
  }
}

// ---------------- LSTM scan, one layer, both directions ----------------
// grid = 128 WGs: blockIdx<64 -> fwd, else bwd. Each WG owns 8 hidden units
// (32 rows of W_hh, register-resident). Sync = data-as-flag via sentinel:
// each thread polls its own 2 dwords of h (single 64-bit load), deposits in
// double-buffered SWIZZLED LDS (chunk stride 68 -> conflict-free b128 reads),
// one barrier, dot from LDS. Gate nonlinearities parallelized across lanes.
__global__ __launch_bounds__(256,1) void k_lstm_scan(
    const float* __restrict__ pre,   // [1024][4096]: dir*2048 + gate*512 + unit
    const float* __restrict__ Whh,   // [2][2048][512] (this layer)
    float* __restrict__ out)         // [1024][1024]; fwd cols 0..511, bwd 512..1023
{
  const int wg  = blockIdx.x;
  const int dir = wg >> 6;
  const int w   = wg & 63;
  const int tid = threadIdx.x;
  const int kc  = tid & 7;         // k-chunk (64 floats)
  const int rl  = tid >> 3;        // local row 0..31
  const int gate= rl & 3;          // i,f,g,o
  const int ul  = rl >> 2;         // local unit 0..7
  const int unit= w*8 + ul;
  const int grow= gate*512 + unit; // row in W_hh

  // swizzled LDS: logical h[i] lives at slot (i>>6)*68 + (i&63).
  // read base for chunk kc = kc*68 -> bank 4*kc -> 8 chunk groups cover all
  // 32 banks exactly once per b128 read (same-kc lanes broadcast).
  __shared__ float hsh[2][544];
  const int wslot = (tid>>5)*68 + ((2*tid)&63);   // write slot for h[2*tid]

  // register-resident weights: this thread's 64 elements of its row
  float wreg[64];
  {
    const float* wp = Whh + ((size_t)dir*2048 + grow)*512 + kc*64;
    #pragma unroll
    for (int j=0;j<16;j++){
      float4 q = *(const float4*)(wp + 4*j);
      wreg[4*j+0]=q.x; wreg[4*j+1]=q.y; wreg[4*j+2]=q.z; wreg[4*j+3]=q.w;
    }
  }

  unsigned* ob = (unsigned*)out;
  const float* prebase = pre + (size_t)dir*2048 + grow;
  float c = 0.f;
  const int base = (tid & 32);     // wave-lane base of this unit's gate group

  for (int t=0;t<1024;t++){
    const int s  = dir ? (1023 - t) : t;
    const int sp = dir ? (s + 1) : (s - 1);

    // prefetch input-projection value (independent of h -> issues before poll)
    float preval = 0.f;
    if (kc==0) preval = prebase[(size_t)s*4096];

    float accv = 0.f;
    if (t > 0){
      // poll ONLY this thread's 2 dwords of h[sp] via one 64-bit load
      unsigned long long* hp64 =
          (unsigned long long*)(ob + (size_t)sp*1024 + dir*512 + 2*tid);
      unsigned long long vv;
      for(;;){
        vv = __hip_atomic_load(hp64, __ATOMIC_RELAXED, __HIP_MEMORY_SCOPE_AGENT);
        if ((unsigned)vv != SENTW && (unsigned)(vv>>32) != SENTW) break;
      }
      float* hb = hsh[t & 1];
      hb[wslot]   = __uint_as_float((unsigned)vv);
      hb[wslot+1] = __uint_as_float((unsigned)(vv>>32));
      __syncthreads();               // LDS copy complete (also fences prev-buf reuse)

      const float* hv = hb + kc*68;
      float p0=0.f,p1=0.f,p2=0.f,p3=0.f;
      #pragma unroll
      for (int j=0;j<16;j++){
        float4 q = *(const float4*)(hv + 4*j);
        p0 = fmaf(wreg[4*j+0], q.x, p0);
        p1 = fmaf(wreg[4*j+1], q.y, p1);
        p2 = fmaf(wreg[4*j+2], q.z, p2);
        p3 = fmaf(wreg[4*j+3], q.w, p3);
      }
      accv = (p0+p1)+(p2+p3);
      accv += __shfl_xor(accv, 1);
      accv += __shfl_xor(accv, 2);
      accv += __shfl_xor(accv, 4);   // lanes with kc==0 hold the full dot
    }
    // per-gate activation on the head lane of each row (parallel across rows)
    float act = 0.f;
    if (kc==0){
      float g = accv + preval;
      act = (gate==2) ? tanhf(g) : sigf(g);
    }
    // gather the 4 activated gates of this unit (lanes base+{0,8,16,24})
    float ai = __shfl(act, base+0);
    float af = __shfl(act, base+8);
    float ag = __shfl(act, base+16);
    float ao = __shfl(act, base+24);
    if ((tid&31)==0){
      c = af*c + ai*ag;
      float h = ao*tanhf(c);
      __hip_atomic_store(ob + (size_t)s*1024 + dir*512 + unit,
                         __float_as_uint(h), __ATOMIC_RELAXED, __HIP_MEMORY_SCOPE_AGENT);
    }
  }
}

// ---------------- row softmax, in place ----------------
__global__ __launch_bounds__(256) void k_softmax(float* __restrict__ P){
  __shared__ float redm[4], reds[4];
  const int i = blockIdx.x, tid = threadIdx.x;
  float4 v = *(float4*)&P[(size_t)i*1024 + tid*4];
  float m = fmaxf(fmaxf(v.x,v.y), fmaxf(v.z,v.w));
  #pragma unroll
  for (int o=32;o;o>>=1) m = fmaxf(m, __shfl_xor(m,o));
  if ((tid&63)==0) redm[tid>>6] = m;
  __syncthreads();
  m = fmaxf(fmaxf(redm[0],redm[1]), fmaxf(redm[2],redm[3]));
  v.x = expf(v.x-m); v.y = expf(v.y-m); v.z = expf(v.z-m); v.w = expf(v.w-m);
  float su = v.x+v.y+v.z+v.w;
  #pragma unroll
  for (int o=32;o;o>>=1) su += __shfl_xor(su,o);
  if ((tid&63)==0) reds[tid>>6] = su;
  __syncthreads();
  su = reds[0]+reds[1]+reds[2]+reds[3];
  float inv = 1.f/su;
  v.x*=inv; v.y*=inv; v.z*=inv; v.w*=inv;
  *(float4*)&P[(size_t)i*1024 + tid*4] = v;
}

extern "C" void kernel_launch(void* const* d_in, const int* in_sizes, int n_in,
                              void* d_out, int out_size, void* d_ws, size_t ws_size,
                              hipStream_t stream)
{
  const int*   x    = (const int*)d_in[0];
  const int*   xp   = (const int*)d_in[1];
  const float* we   = (const float*)d_in[2];
  const float* pe   = (const float*)d_in[3];
  const float* Wih  = (const float*)d_in[4];   // [2][2][2048][1024]
  const float* Whh  = (const float*)d_in[5];   // [2][2][2048][512]
  const float* bl   = (const float*)d_in[6];   // [2][2][2048]
  const float* Wh   = (const float*)d_in[7];
  const float* bh   = (const float*)d_in[8];
  const float* Wd   = (const float*)d_in[9];
  const float* bd   = (const float*)d_in[10];
  const float* Wbi  = (const float*)d_in[11];
  const float* bbi  = (const float*)d_in[12];
  float* outp = (float*)d_out;

  // workspace layout (28 MB), with reuse after the scans:
  char* ws = (char*)d_ws;
  float* X0   = (float*)(ws);                  // [0,4M)   embeddings
  float* pre  = (float*)(ws + ((size_t)4<<20));// [4M,20M) input projections
  float* out0 = (float*)(ws + ((size_t)20<<20));// [20M,24M)
  float* out1 = (float*)(ws + ((size_t)24<<20));// [24M,28M)
  float* head = (float*)(ws);                  // reuse [0,4M)
  float* dep  = (float*)(ws + ((size_t)4<<20));// reuse [4M,8M)
  float* Ubuf = (float*)(ws + ((size_t)8<<20));// reuse [8M,12M)

  // sentinel-init the scan outputs (data-as-flag scheme), every launch
  hipMemsetAsync(out0, 0x7F, (size_t)4<<20, stream);
  hipMemsetAsync(out1, 0x7F, (size_t)4<<20, stream);

  dim3 blk(256);
  k_embed<<<1024, blk, 0, stream>>>(x, xp, we, pe, X0);

  // layer 0: pre = X0 * Wih[0]^T + b[0]  (both dirs stacked: N=4096)
  k_gemm_abT<<<dim3(32,8), blk, 0, stream>>>(X0, Wih, pre, 1024, 4096, 1024, bl, nullptr);
  k_lstm_scan<<<128, blk, 0, stream>>>(pre, Whh, out0);

  // layer 1
  k_gemm_abT<<<dim3(32,8), blk, 0, stream>>>(out0, Wih + (size_t)4096*1024, pre,
                                             1024, 4096, 1024, bl + 4096, nullptr);
  k_lstm_scan<<<128, blk, 0, stream>>>(pre, Whh + (size_t)2*2048*512, out1);

  // biaffine: head = out1*Wh^T+bh ; dep = out1*Wd^T+bd ; U = dep*Wbi^T ; scores = head*U^T + bbi
  k_gemm_abT<<<dim3(8,8), blk, 0, stream>>>(out1, Wh, head, 1024, 1024, 1024, bh, nullptr);
  k_gemm_abT<<<dim3(8,8), blk, 0, stream>>>(out1, Wd, dep,  1024, 1024, 1024, bd, nullptr);
  k_gemm_abT<<<dim3(8,8), blk, 0, stream>>>(dep,  Wbi, Ubuf,1024, 1024, 1024, nullptr, nullptr);
  k_gemm_abT<<<dim3(8,8), blk, 0, stream>>>(head, Ubuf, outp,1024, 1024, 1024, nullptr, bbi);

  k_softmax<<<1024, blk, 0, stream>>>(outp);
}